// Round 10
// baseline (219.430 us; speedup 1.0000x reference)
//
#include <hip/hip_runtime.h>
#include <cmath>

#define B_ 512
#define EPS_ 1e-8f

typedef __bf16 bf16x8 __attribute__((ext_vector_type(8)));
typedef float f32x4 __attribute__((ext_vector_type(4)));
typedef unsigned uint32x4_ __attribute__((ext_vector_type(4)));

__device__ __forceinline__ float sigmoidf_(float x) { return 1.f / (1.f + expf(-x)); }
__device__ __forceinline__ float softplusf_(float x) { return x > 20.f ? x : log1pf(expf(x)); }
__device__ __forceinline__ unsigned f2bf(float x) {
  union { float f; unsigned u; } v; v.f = x;
  unsigned r = v.u + 0x7FFF + ((v.u >> 16) & 1);
  return r >> 16;
}
__device__ __forceinline__ float bfhi2f(unsigned u) { return __uint_as_float(u & 0xffff0000u); }
__device__ __forceinline__ float bflo2f(unsigned u) { return __uint_as_float(u << 16); }
// packed f32->bf16 (RNE), lo = a, hi = b
__device__ __forceinline__ unsigned cvtpk(float a, float b) {
  unsigned r;
  asm("v_cvt_pk_bf16_f32 %0, %1, %2" : "=v"(r) : "v"(a), "v"(b));
  return r;
}

// ---------------- one prep kernel: x2b + all weight conversions (grid-stride)
__global__ void k_prep(const float* __restrict__ in_data, const float* __restrict__ prev_reads,
                       const float* __restrict__ h0,
                       const float* __restrict__ W_ih, const float* __restrict__ W_hh,
                       const float* __restrict__ b_ih, const float* __restrict__ b_hh,
                       const float* __restrict__ W_rh, const float* __restrict__ W_wh,
                       const float* __restrict__ W_out,
                       const float* __restrict__ b_rh, const float* __restrict__ b_wh,
                       unsigned short* __restrict__ x2b,
                       unsigned short* __restrict__ Wcatb, float* __restrict__ bcat,
                       unsigned short* __restrict__ W2b, unsigned short* __restrict__ Woutb,
                       float* __restrict__ bcat2) {
  const int stride = gridDim.x * blockDim.x;
  const int t0 = blockIdx.x * blockDim.x + threadIdx.x;
  for (int i = t0; i < 512 * 1024; i += stride) {
    const int b = i >> 10, j = i & 1023;
    float v;
    if (j < 256) v = in_data[(size_t)b * 256 + j];
    else if (j < 512) { const int jj = j - 256; v = prev_reads[(size_t)(jj >> 6) * B_ * 64 + (size_t)b * 64 + (jj & 63)]; }
    else v = h0[(size_t)b * 512 + (j - 512)];
    x2b[i] = (unsigned short)f2bf(v);
  }
  for (int i = t0; i < 2048 * 1024; i += stride) {
    const int j = i >> 10, k = i & 1023;
    Wcatb[i] = (unsigned short)f2bf(k < 512 ? W_ih[(size_t)j * 512 + k] : W_hh[(size_t)j * 512 + (k - 512)]);
  }
  for (int i = t0; i < 2048; i += stride) bcat[i] = b_ih[i] + b_hh[i];
  for (int i = t0; i < 143360; i += stride) W2b[i] = (unsigned short)f2bf(W_rh[i]);
  for (int i = t0; i < 405504; i += stride) W2b[143360 + i] = (unsigned short)f2bf(W_wh[i]);
  for (int i = t0; i < 196608; i += stride) Woutb[i] = (unsigned short)f2bf(W_out[i]);
  for (int i = t0; i < 280; i += stride) bcat2[i] = b_rh[i];
  for (int i = t0; i < 792; i += stride) bcat2[280 + i] = b_wh[i];
}

// ---------------- bf16 MFMA GEMM, one wave per 32x32 tile, direct-from-global frags
template <bool SIG>
__global__ __launch_bounds__(64) void k_gemm_mfma(const unsigned short* __restrict__ A, int lda,
                                                  const unsigned short* __restrict__ W,
                                                  const float* __restrict__ bias,
                                                  float* __restrict__ C,
                                                  int Nn, int Kk, int ldc) {
  const int l = threadIdx.x;
  const int m0 = blockIdx.y * 32, n0 = blockIdx.x * 32;
  const int lr = l & 15, lk = (l >> 4) * 8;
  f32x4 acc00 = {0.f, 0.f, 0.f, 0.f}, acc01 = acc00, acc10 = acc00, acc11 = acc00;
  const size_t pa0 = (size_t)(m0 + lr) * lda + lk;
  const size_t pa1 = pa0 + (size_t)16 * lda;
  const bool bok0 = (n0 + lr) < Nn, bok1 = (n0 + 16 + lr) < Nn;
  const size_t pb0 = (size_t)(n0 + lr) * Kk + lk;
  const size_t pb1 = pb0 + (size_t)16 * Kk;
#pragma unroll 4
  for (int k0 = 0; k0 < Kk; k0 += 32) {
    bf16x8 a0 = *(const bf16x8*)(A + pa0 + k0);
    bf16x8 a1 = *(const bf16x8*)(A + pa1 + k0);
    bf16x8 b0 = {}, b1 = {};
    if (bok0) b0 = *(const bf16x8*)(W + pb0 + k0);
    if (bok1) b1 = *(const bf16x8*)(W + pb1 + k0);
    acc00 = __builtin_amdgcn_mfma_f32_16x16x32_bf16(a0, b0, acc00, 0, 0, 0);
    acc01 = __builtin_amdgcn_mfma_f32_16x16x32_bf16(a0, b1, acc01, 0, 0, 0);
    acc10 = __builtin_amdgcn_mfma_f32_16x16x32_bf16(a1, b0, acc10, 0, 0, 0);
    acc11 = __builtin_amdgcn_mfma_f32_16x16x32_bf16(a1, b1, acc11, 0, 0, 0);
  }
  const int orow = (l >> 4) * 4;
  f32x4 accs[2][2] = {{acc00, acc01}, {acc10, acc11}};
#pragma unroll
  for (int mi = 0; mi < 2; ++mi) {
#pragma unroll
    for (int nj = 0; nj < 2; ++nj) {
      const int n = n0 + nj * 16 + lr;
      if (n < Nn) {
        const float bv = bias[n];
#pragma unroll
        for (int r = 0; r < 4; ++r) {
          const int m = m0 + mi * 16 + orow + r;
          float v = accs[mi][nj][r] + bv;
          if (SIG) v = 1.f / (1.f + expf(-v));
          C[(size_t)m * ldc + n] = v;
        }
      }
    }
  }
}

// ---------------- LSTM pointwise -> h (bf16) into Aoutb rows (stride 768)
__global__ void k_lstm(const float* __restrict__ gates, const float* __restrict__ c0,
                       unsigned short* __restrict__ Aoutb) {
  const int idx = blockIdx.x * blockDim.x + threadIdx.x;  // < 512*512
  const int b = idx >> 9, j = idx & 511;
  const float* g = gates + (size_t)b * 2048;
  const float ig = g[j], fg = g[512 + j], gg = g[1024 + j], og = g[1536 + j];
  const float c = sigmoidf_(fg) * c0[idx] + sigmoidf_(ig) * tanhf(gg);
  Aoutb[(size_t)b * 768 + j] = (unsigned short)f2bf(sigmoidf_(og) * tanhf(c));
}

// ---------------- fused NTM head loop: one 1024-thread block (16 waves) per b.
// Memory image in REGISTERS, MFMA A-frag layout, 4 tiles/wave = 32 VGPR/lane.
// 3 __syncthreads per head (S1 exp partials, S2 sharpen partials, S3 sweep+scores).
// prevw staged to LDS in phase 1 so phase 2 has no global loads on the
// inter-barrier critical path.
// LAUNCH BOUNDS SEMANTICS (measured r7-r9): 2nd arg acts as CUDA
// minBlocksPerCU. (512,4)->64 VGPR, (512,2)->128, (1024,4)->clamped 2 blk
// -> 64 VGPR + image spill (1 GB scratch). (1024,1) -> 16 waves/CU -> 128
// VGPR cap, image fits. DO NOT raise the 2nd arg.
__global__ __launch_bounds__(1024, 1) void k_mega(const float* __restrict__ mem0,
                                                  const float* __restrict__ P,
                                                  const float* __restrict__ prev_w_r,
                                                  const float* __restrict__ prev_w_w,
                                                  unsigned short* __restrict__ Aoutb) {
  const int b = blockIdx.x;
  const int t = threadIdx.x;   // 1024
  const int l = t & 63;
  const int w = t >> 6;        // wave 0..15
  const int p = l & 15;        // frag row within tile
  const int q = l >> 4;        // k-chunk

  __shared__ float Ar[1024], Aw[1024];         // scores -> pe (unscaled exp)
  __shared__ float nrm_s[1024];                // norms -> wpR
  __shared__ float wp2[1024];                  // wpW
  __shared__ float pwb[2][1024];               // staged prevw rows (r/w)
  __shared__ float racc[16][64];
  __shared__ float knb[8][64];
  __shared__ float parb[8][8];
  __shared__ float eb[4][64], ab[4][64];
  __shared__ float redB[16], redC[16];

  // ---- stage memory rows into register fragments (f32 global -> packed bf16)
  uint32x4_ va[4], vb[4];
  {
    const float* src = mem0 + (size_t)b * 65536;
#pragma unroll
    for (int tt = 0; tt < 4; ++tt) {
      const float* rp = src + ((w * 4 + tt) * 16 + p) * 64;
      const float4 f0 = *(const float4*)(rp + q * 8);
      const float4 f1 = *(const float4*)(rp + q * 8 + 4);
      const float4 f2 = *(const float4*)(rp + 32 + q * 8);
      const float4 f3 = *(const float4*)(rp + 32 + q * 8 + 4);
      va[tt][0] = cvtpk(f0.x, f0.y); va[tt][1] = cvtpk(f0.z, f0.w);
      va[tt][2] = cvtpk(f1.x, f1.y); va[tt][3] = cvtpk(f1.z, f1.w);
      vb[tt][0] = cvtpk(f2.x, f2.y); vb[tt][1] = cvtpk(f2.z, f2.w);
      vb[tt][2] = cvtpk(f3.x, f3.y); vb[tt][3] = cvtpk(f3.z, f3.w);
    }
  }

  // ---- params phase (waves 0..7: unit = type*4+head)
  if (w < 8) {
    const int type = w >> 2, head = w & 3;
    const float* pp = P + (size_t)b * 1072 + (type == 0 ? head * 70 : 280 + head * 198);
    const float kv = tanhf(pp[l]);
    float ss = kv * kv;
#pragma unroll
    for (int off = 32; off > 0; off >>= 1) ss += __shfl_xor(ss, off);
    knb[w][l] = kv / (sqrtf(ss) + EPS_);
    if (l == 0) {
      parb[w][0] = softplusf_(pp[64]);
      parb[w][1] = sigmoidf_(pp[65]);
      const float s0 = pp[66], s1 = pp[67], s2 = pp[68];
      const float mx = fmaxf(s0, fmaxf(s1, s2));
      const float e0 = expf(s0 - mx), e1 = expf(s1 - mx), e2 = expf(s2 - mx);
      const float inv = 1.f / (e0 + e1 + e2);
      parb[w][2] = e0 * inv; parb[w][3] = e1 * inv; parb[w][4] = e2 * inv;
      parb[w][5] = 1.f + softplusf_(pp[69]);
    }
    if (type == 1) {
      eb[head][l] = sigmoidf_(pp[70 + l]);
      ab[head][l] = tanhf(pp[134 + l]);
    }
  }
  __syncthreads();

  // ---- key B-fragments (cols 0..3 read keys, 4..7 write keys, 8..15 zero)
  bf16x8 kb0 = {}, kb1 = {};
  {
    const int c = l & 15, ks = (l >> 4) * 8;
    if (c < 8) {
#pragma unroll
      for (int j = 0; j < 8; ++j) {
        kb0[j] = (__bf16)knb[c][ks + j];
        kb1[j] = (__bf16)knb[c][32 + ks + j];
      }
    }
  }

  // ---- MFMA score pass from registers: scores for head hj + Gram-diag norms
  auto score_pass = [&](int hj) {
#pragma unroll
    for (int tt = 0; tt < 4; ++tt) {
      const int tile = w * 4 + tt;
      const bf16x8 a0 = __builtin_bit_cast(bf16x8, va[tt]);
      const bf16x8 a1 = __builtin_bit_cast(bf16x8, vb[tt]);
      f32x4 sacc = {0.f, 0.f, 0.f, 0.f}, gacc = {0.f, 0.f, 0.f, 0.f};
      sacc = __builtin_amdgcn_mfma_f32_16x16x32_bf16(a0, kb0, sacc, 0, 0, 0);
      sacc = __builtin_amdgcn_mfma_f32_16x16x32_bf16(a1, kb1, sacc, 0, 0, 0);
      gacc = __builtin_amdgcn_mfma_f32_16x16x32_bf16(a0, a0, gacc, 0, 0, 0);
      gacc = __builtin_amdgcn_mfma_f32_16x16x32_bf16(a1, a1, gacc, 0, 0, 0);
      if (p == hj)        *(f32x4*)&Ar[tile * 16 + q * 4] = sacc;
      if (p == 4 + hj)    *(f32x4*)&Aw[tile * 16 + q * 4] = sacc;
      if ((p >> 2) == q)  nrm_s[tile * 16 + p] = gacc[p & 3];
    }
  };

  score_pass(0);
  __syncthreads();  // scores + norms ready for head 0

  const int h = t >> 9;      // 0: read-type half (waves 0-7), 1: write-type half
  const int th = t & 511;
  float* Abuf = h ? Aw : Ar;     // pe buffer
  float* Wbuf = h ? wp2 : nrm_s; // wp buffer

  for (int i = 0; i < 4; ++i) {
    const float beta = parb[h * 4 + i][0], g = parb[h * 4 + i][1];
    const float sh0 = parb[h * 4 + i][2], sh1 = parb[h * 4 + i][3], sh2 = parb[h * 4 + i][4];
    const float gamma = parb[h * 4 + i][5];
    const float* prevw = (h ? prev_w_w : prev_w_r) + ((size_t)i * 512 + b) * 1024;

    // ---- phase 1: stage prevw -> LDS (issue early) + unscaled exp of scores
    const float pv0 = prevw[th];
    const float pv1 = prevw[th + 512];
    float e2[2];
    float s = 0.f;
#pragma unroll
    for (int k = 0; k < 2; ++k) {
      const int u = th + 512 * k;
      const float z = beta * Abuf[u] / (sqrtf(nrm_s[u]) + EPS_);
      e2[k] = __expf(z);
      s += e2[k];
    }
#pragma unroll
    for (int k = 0; k < 2; ++k) Abuf[th + 512 * k] = e2[k];
    pwb[h][th] = pv0;
    pwb[h][th + 512] = pv1;
#pragma unroll
    for (int off = 32; off > 0; off >>= 1) s += __shfl_xor(s, off);
    if (l == 0) redB[w] = s;
    __syncthreads();  // S1: pe + pw + exp partials visible

    // ---- phase 2: gate + shift + sharpen (softmax scale folded into gi)
    float gsum = 0.f;
#pragma unroll
    for (int j = 0; j < 8; ++j) gsum += redB[h * 8 + j];
    const float gi = g / gsum;
    const float gm = 1.f - g;
    const float* pw = pwb[h];
    float wpv[2];
    float s2 = 0.f;
#pragma unroll
    for (int k = 0; k < 2; ++k) {
      const int u = th + 512 * k;
      const int um = (u + 1023) & 1023, up = (u + 1) & 1023;
      const float wgm = gi * Abuf[um] + gm * pw[um];
      const float wg0 = gi * Abuf[u] + gm * pw[u];
      const float wgp = gi * Abuf[up] + gm * pw[up];
      const float ws = sh0 * wgm + sh1 * wg0 + sh2 * wgp;
      wpv[k] = (ws > 0.f) ? exp2f(gamma * __log2f(ws)) : 0.f;
      s2 += wpv[k];
    }
#pragma unroll
    for (int k = 0; k < 2; ++k) Wbuf[th + 512 * k] = wpv[k];
#pragma unroll
    for (int off = 32; off > 0; off >>= 1) s2 += __shfl_xor(s2, off);
    if (l == 0) redC[w] = s2;
    __syncthreads();  // S2: wp + sharpen partials visible

    // ---- phase 3: sweep (reads + in-register update, weights scaled read-side)
    float ir = 0.f, iw = 0.f;
#pragma unroll
    for (int j = 0; j < 8; ++j) { ir += redC[j]; iw += redC[8 + j]; }
    const float inv2r = 1.f / (ir + EPS_);
    const float inv2w = 1.f / (iw + EPS_);

    uint32x4_ epk0 = {}, epk1 = {}, apk0 = {}, apk1 = {};
    if (i < 3) {
#pragma unroll
      for (int j = 0; j < 4; ++j) {
        epk0[j] = cvtpk(eb[i][q * 8 + 2 * j], eb[i][q * 8 + 2 * j + 1]);
        epk1[j] = cvtpk(eb[i][32 + q * 8 + 2 * j], eb[i][32 + q * 8 + 2 * j + 1]);
        apk0[j] = cvtpk(ab[i][q * 8 + 2 * j], ab[i][q * 8 + 2 * j + 1]);
        apk1[j] = cvtpk(ab[i][32 + q * 8 + 2 * j], ab[i][32 + q * 8 + 2 * j + 1]);
      }
    }

    float r[16] = {0.f, 0.f, 0.f, 0.f, 0.f, 0.f, 0.f, 0.f,
                   0.f, 0.f, 0.f, 0.f, 0.f, 0.f, 0.f, 0.f};
#pragma unroll
    for (int tt = 0; tt < 4; ++tt) {
      const int row = (w * 4 + tt) * 16 + p;
      const float wr = nrm_s[row] * inv2r;
      const float ww = (i < 3) ? wp2[row] * inv2w : 0.f;
#pragma unroll
      for (int wd = 0; wd < 4; ++wd) {
        const unsigned uv = va[tt][wd];
        const float v0 = bflo2f(uv), v1 = bfhi2f(uv);
        r[wd * 2 + 0] = fmaf(wr, v0, r[wd * 2 + 0]);
        r[wd * 2 + 1] = fmaf(wr, v1, r[wd * 2 + 1]);
        if (i < 3) {
          const unsigned ue = epk0[wd], ua = apk0[wd];
          const float n0 = fmaf(v0, fmaf(-ww, bflo2f(ue), 1.f), ww * bflo2f(ua));
          const float n1 = fmaf(v1, fmaf(-ww, bfhi2f(ue), 1.f), ww * bfhi2f(ua));
          va[tt][wd] = cvtpk(n0, n1);
        }
      }
#pragma unroll
      for (int wd = 0; wd < 4; ++wd) {
        const unsigned uv = vb[tt][wd];
        const float v0 = bflo2f(uv), v1 = bfhi2f(uv);
        r[8 + wd * 2 + 0] = fmaf(wr, v0, r[8 + wd * 2 + 0]);
        r[8 + wd * 2 + 1] = fmaf(wr, v1, r[8 + wd * 2 + 1]);
        if (i < 3) {
          const unsigned ue = epk1[wd], ua = apk1[wd];
          const float n0 = fmaf(v0, fmaf(-ww, bflo2f(ue), 1.f), ww * bflo2f(ua));
          const float n1 = fmaf(v1, fmaf(-ww, bfhi2f(ue), 1.f), ww * bfhi2f(ua));
          vb[tt][wd] = cvtpk(n0, n1);
        }
      }
    }

    // ---- fold 16 col-partials across the 16 lanes of each q-group
#pragma unroll
    for (int j = 0; j < 8; ++j) {
      const float send = (p & 1) ? r[j] : r[j + 8];
      r[j] = ((p & 1) ? r[j + 8] : r[j]) + __shfl_xor(send, 1);
    }
#pragma unroll
    for (int j = 0; j < 4; ++j) {
      const float send = (p & 2) ? r[j] : r[j + 4];
      r[j] = ((p & 2) ? r[j + 4] : r[j]) + __shfl_xor(send, 2);
    }
#pragma unroll
    for (int j = 0; j < 2; ++j) {
      const float send = (p & 4) ? r[j] : r[j + 2];
      r[j] = ((p & 4) ? r[j + 2] : r[j]) + __shfl_xor(send, 4);
    }
    {
      const float send = (p & 8) ? r[0] : r[1];
      r[0] = ((p & 8) ? r[1] : r[0]) + __shfl_xor(send, 8);
    }
    {
      const int idx = ((p & 1) << 3) | ((p & 2) << 1) | ((p & 4) >> 1) | ((p & 8) >> 3);
      const int col = (idx & 8) ? (32 + q * 8 + (idx & 7)) : (q * 8 + idx);
      racc[w][col] = r[0];
    }

    if (i < 3) score_pass(i + 1);  // next head's scores/norms from updated regs
    __syncthreads();               // S3: racc + next scores visible

    if (t < 64) {
      float s3 = 0.f;
#pragma unroll
      for (int wv = 0; wv < 16; ++wv) s3 += racc[wv][t];
      Aoutb[(size_t)b * 768 + 512 + i * 64 + t] = (unsigned short)f2bf(s3);
    }
  }
}

extern "C" void kernel_launch(void* const* d_in, const int* in_sizes, int n_in,
                              void* d_out, int out_size, void* d_ws, size_t ws_size,
                              hipStream_t stream) {
  (void)in_sizes; (void)n_in; (void)out_size; (void)ws_size;
  const float* in_data = (const float*)d_in[0];
  const float* memory = (const float*)d_in[1];
  const float* prev_reads = (const float*)d_in[2];
  const float* prev_w_r = (const float*)d_in[3];
  const float* prev_w_w = (const float*)d_in[4];
  const float* h0 = (const float*)d_in[5];
  const float* c0 = (const float*)d_in[6];
  const float* W_ih = (const float*)d_in[7];
  const float* b_ih = (const float*)d_in[8];
  const float* W_hh = (const float*)d_in[9];
  const float* b_hh = (const float*)d_in[10];
  const float* W_rh = (const float*)d_in[11];
  const float* b_rh = (const float*)d_in[12];
  const float* W_wh = (const float*)d_in[13];
  const float* b_wh = (const float*)d_in[14];
  const float* W_out = (const float*)d_in[15];
  const float* b_out = (const float*)d_in[16];
  float* out = (float*)d_out;

  char* base = (char*)d_ws;
  auto alloc = [&](size_t bytes) -> char* {
    char* p = base; base += (bytes + 255) & ~(size_t)255; return p;
  };
  unsigned short* x2b   = (unsigned short*)alloc((size_t)512 * 1024 * 2);
  unsigned short* Wcatb = (unsigned short*)alloc((size_t)2048 * 1024 * 2);
  float* bcat           = (float*)alloc(2048 * 4);
  float* gates          = (float*)alloc((size_t)512 * 2048 * 4);
  unsigned short* W2b   = (unsigned short*)alloc((size_t)1072 * 512 * 2);
  float* bcat2          = (float*)alloc(1072 * 4);
  unsigned short* Woutb = (unsigned short*)alloc((size_t)256 * 768 * 2);
  float* P              = (float*)alloc((size_t)512 * 1072 * 4);
  unsigned short* Aoutb = (unsigned short*)alloc((size_t)512 * 768 * 2);

  k_prep<<<2048, 256, 0, stream>>>(in_data, prev_reads, h0, W_ih, W_hh, b_ih, b_hh,
                                   W_rh, W_wh, W_out, b_rh, b_wh,
                                   x2b, Wcatb, bcat, W2b, Woutb, bcat2);
  k_gemm_mfma<false><<<dim3(64, 16), 64, 0, stream>>>(x2b, 1024, Wcatb, bcat, gates, 2048, 1024, 2048);
  k_lstm<<<1024, 256, 0, stream>>>(gates, c0, Aoutb);
  k_gemm_mfma<false><<<dim3(34, 16), 64, 0, stream>>>(Aoutb, 768, W2b, bcat2, P, 1072, 512, 1072);
  k_mega<<<512, 1024, 0, stream>>>(memory, P, prev_w_r, prev_w_w, Aoutb);
  k_gemm_mfma<true><<<dim3(8, 16), 64, 0, stream>>>(Aoutb, 768, Woutb, b_out, out, 256, 768, 256);
}

// Round 11
// 123.033 us; speedup vs baseline: 1.7835x; 1.7835x over previous
//
#include <hip/hip_runtime.h>
#include <cmath>

#define B_ 512
#define EPS_ 1e-8f

typedef __bf16 bf16x8 __attribute__((ext_vector_type(8)));
typedef float f32x4 __attribute__((ext_vector_type(4)));

__device__ __forceinline__ float sigmoidf_(float x) { return 1.f / (1.f + expf(-x)); }
__device__ __forceinline__ float softplusf_(float x) { return x > 20.f ? x : log1pf(expf(x)); }
__device__ __forceinline__ unsigned f2bf(float x) {
  union { float f; unsigned u; } v; v.f = x;
  unsigned r = v.u + 0x7FFF + ((v.u >> 16) & 1);
  return r >> 16;
}
__device__ __forceinline__ float bfhi2f(unsigned u) { return __uint_as_float(u & 0xffff0000u); }
__device__ __forceinline__ float bflo2f(unsigned u) { return __uint_as_float(u << 16); }
// packed f32->bf16 (RNE), lo = a, hi = b
__device__ __forceinline__ unsigned cvtpk(float a, float b) {
  unsigned r;
  asm("v_cvt_pk_bf16_f32 %0, %1, %2" : "=v"(r) : "v"(a), "v"(b));
  return r;
}

// ---------------- one prep kernel: x2b + all weight conversions (grid-stride)
__global__ void k_prep(const float* __restrict__ in_data, const float* __restrict__ prev_reads,
                       const float* __restrict__ h0,
                       const float* __restrict__ W_ih, const float* __restrict__ W_hh,
                       const float* __restrict__ b_ih, const float* __restrict__ b_hh,
                       const float* __restrict__ W_rh, const float* __restrict__ W_wh,
                       const float* __restrict__ W_out,
                       const float* __restrict__ b_rh, const float* __restrict__ b_wh,
                       unsigned short* __restrict__ x2b,
                       unsigned short* __restrict__ Wcatb, float* __restrict__ bcat,
                       unsigned short* __restrict__ W2b, unsigned short* __restrict__ Woutb,
                       float* __restrict__ bcat2) {
  const int stride = gridDim.x * blockDim.x;
  const int t0 = blockIdx.x * blockDim.x + threadIdx.x;
  for (int i = t0; i < 512 * 1024; i += stride) {
    const int b = i >> 10, j = i & 1023;
    float v;
    if (j < 256) v = in_data[(size_t)b * 256 + j];
    else if (j < 512) { const int jj = j - 256; v = prev_reads[(size_t)(jj >> 6) * B_ * 64 + (size_t)b * 64 + (jj & 63)]; }
    else v = h0[(size_t)b * 512 + (j - 512)];
    x2b[i] = (unsigned short)f2bf(v);
  }
  for (int i = t0; i < 2048 * 1024; i += stride) {
    const int j = i >> 10, k = i & 1023;
    Wcatb[i] = (unsigned short)f2bf(k < 512 ? W_ih[(size_t)j * 512 + k] : W_hh[(size_t)j * 512 + (k - 512)]);
  }
  for (int i = t0; i < 2048; i += stride) bcat[i] = b_ih[i] + b_hh[i];
  for (int i = t0; i < 143360; i += stride) W2b[i] = (unsigned short)f2bf(W_rh[i]);
  for (int i = t0; i < 405504; i += stride) W2b[143360 + i] = (unsigned short)f2bf(W_wh[i]);
  for (int i = t0; i < 196608; i += stride) Woutb[i] = (unsigned short)f2bf(W_out[i]);
  for (int i = t0; i < 280; i += stride) bcat2[i] = b_rh[i];
  for (int i = t0; i < 792; i += stride) bcat2[280 + i] = b_wh[i];
}

// ---------------- bf16 MFMA GEMM, one wave per 32x32 tile, direct-from-global frags
template <bool SIG>
__global__ __launch_bounds__(64) void k_gemm_mfma(const unsigned short* __restrict__ A, int lda,
                                                  const unsigned short* __restrict__ W,
                                                  const float* __restrict__ bias,
                                                  float* __restrict__ C,
                                                  int Nn, int Kk, int ldc) {
  const int l = threadIdx.x;
  const int m0 = blockIdx.y * 32, n0 = blockIdx.x * 32;
  const int lr = l & 15, lk = (l >> 4) * 8;
  f32x4 acc00 = {0.f, 0.f, 0.f, 0.f}, acc01 = acc00, acc10 = acc00, acc11 = acc00;
  const size_t pa0 = (size_t)(m0 + lr) * lda + lk;
  const size_t pa1 = pa0 + (size_t)16 * lda;
  const bool bok0 = (n0 + lr) < Nn, bok1 = (n0 + 16 + lr) < Nn;
  const size_t pb0 = (size_t)(n0 + lr) * Kk + lk;
  const size_t pb1 = pb0 + (size_t)16 * Kk;
#pragma unroll 4
  for (int k0 = 0; k0 < Kk; k0 += 32) {
    bf16x8 a0 = *(const bf16x8*)(A + pa0 + k0);
    bf16x8 a1 = *(const bf16x8*)(A + pa1 + k0);
    bf16x8 b0 = {}, b1 = {};
    if (bok0) b0 = *(const bf16x8*)(W + pb0 + k0);
    if (bok1) b1 = *(const bf16x8*)(W + pb1 + k0);
    acc00 = __builtin_amdgcn_mfma_f32_16x16x32_bf16(a0, b0, acc00, 0, 0, 0);
    acc01 = __builtin_amdgcn_mfma_f32_16x16x32_bf16(a0, b1, acc01, 0, 0, 0);
    acc10 = __builtin_amdgcn_mfma_f32_16x16x32_bf16(a1, b0, acc10, 0, 0, 0);
    acc11 = __builtin_amdgcn_mfma_f32_16x16x32_bf16(a1, b1, acc11, 0, 0, 0);
  }
  const int orow = (l >> 4) * 4;
  f32x4 accs[2][2] = {{acc00, acc01}, {acc10, acc11}};
#pragma unroll
  for (int mi = 0; mi < 2; ++mi) {
#pragma unroll
    for (int nj = 0; nj < 2; ++nj) {
      const int n = n0 + nj * 16 + lr;
      if (n < Nn) {
        const float bv = bias[n];
#pragma unroll
        for (int r = 0; r < 4; ++r) {
          const int m = m0 + mi * 16 + orow + r;
          float v = accs[mi][nj][r] + bv;
          if (SIG) v = 1.f / (1.f + expf(-v));
          C[(size_t)m * ldc + n] = v;
        }
      }
    }
  }
}

// ---------------- LSTM pointwise -> h (bf16) into Aoutb rows (stride 768)
__global__ void k_lstm(const float* __restrict__ gates, const float* __restrict__ c0,
                       unsigned short* __restrict__ Aoutb) {
  const int idx = blockIdx.x * blockDim.x + threadIdx.x;  // < 512*512
  const int b = idx >> 9, j = idx & 511;
  const float* g = gates + (size_t)b * 2048;
  const float ig = g[j], fg = g[512 + j], gg = g[1024 + j], og = g[1536 + j];
  const float c = sigmoidf_(fg) * c0[idx] + sigmoidf_(ig) * tanhf(gg);
  Aoutb[(size_t)b * 768 + j] = (unsigned short)f2bf(sigmoidf_(og) * tanhf(c));
}

// ---------------- fused NTM head loop: one 1024-thread block per batch row.
// LDS bf16 memory image (XOR-swizzled 16B chunks), MFMA scores + Gram norms.
// 3 barriers/head: S1 (unscaled-exp pe + prevw staged bf16), S2 (wp sharpen,
// softmax scale folded into gate), S3 (sweep with read-side 1/sum + next-head
// score_pass on wave-owned rows + racc).
// NOTE (r7-r10): 1024-thread blocks are HARD-CAPPED at 64 VGPR regardless of
// launch_bounds 2nd arg; register-resident memory images spill (1 GB scratch).
// This kernel keeps the image in LDS and needs ~52 VGPR — safe.
__global__ __launch_bounds__(1024, 4) void k_mega(const float* __restrict__ mem0,
                                                  const float* __restrict__ P,
                                                  const float* __restrict__ prev_w_r,
                                                  const float* __restrict__ prev_w_w,
                                                  unsigned short* __restrict__ Aoutb) {
  const int b = blockIdx.x;
  const int t = threadIdx.x;   // 1024
  const int l = t & 63;
  const int w = t >> 6;        // wave 0..15
  const int p = l & 15;
  const int q = l >> 4;        // 0..3

  __shared__ unsigned short smem[65536];                 // 1024x64 bf16 image (128 KB)
  __shared__ float Ar[1024], Aw[1024];                   // scores -> pe
  __shared__ float nrm_s[1024];                          // Gram-diag norms
  __shared__ float wpR[1024], wpW[1024];                 // unnormalized final weights
  __shared__ float racc[16][64];
  __shared__ unsigned short knbs[512];                   // 8 keys x 64 cols (bf16)
  __shared__ float parb[8][8];
  __shared__ unsigned ebp[4][32], abp[4][32];            // packed bf16 erase/add
  __shared__ unsigned short pwbs[2][1024];               // staged prevw (bf16)
  __shared__ float redB[16], redC[16];

  // ---- params phase (waves 0..7: unit = type*4+head)
  if (w < 8) {
    const int type = w >> 2, head = w & 3;
    const float* pp = P + (size_t)b * 1072 + (type == 0 ? head * 70 : 280 + head * 198);
    const float kv = tanhf(pp[l]);
    float ss = kv * kv;
#pragma unroll
    for (int off = 32; off > 0; off >>= 1) ss += __shfl_xor(ss, off);
    knbs[w * 64 + l] = (unsigned short)f2bf(kv / (sqrtf(ss) + EPS_));
    if (l == 0) {
      parb[w][0] = softplusf_(pp[64]);
      parb[w][1] = sigmoidf_(pp[65]);
      const float s0 = pp[66], s1 = pp[67], s2 = pp[68];
      const float mx = fmaxf(s0, fmaxf(s1, s2));
      const float e0 = expf(s0 - mx), e1 = expf(s1 - mx), e2 = expf(s2 - mx);
      const float inv = 1.f / (e0 + e1 + e2);
      parb[w][2] = e0 * inv; parb[w][3] = e1 * inv; parb[w][4] = e2 * inv;
      parb[w][5] = 1.f + softplusf_(pp[69]);
    }
    if (type == 1 && l < 32) {
      ebp[head][l] = cvtpk(sigmoidf_(pp[70 + 2 * l]), sigmoidf_(pp[70 + 2 * l + 1]));
      abp[head][l] = cvtpk(tanhf(pp[134 + 2 * l]), tanhf(pp[134 + 2 * l + 1]));
    }
  }

  // ---- staging: f32 memory -> bf16 LDS image (swizzled 16B chunks)
  {
    const float4* src = (const float4*)(mem0 + (size_t)b * 65536);
#pragma unroll 4
    for (int k = 0; k < 16; ++k) {
      const int v = k * 1024 + t;          // float4 index; n = v>>4, ch = v&15
      const float4 f = src[v];
      const int n = v >> 4, ch = v & 15;
      uint2 pk;
      pk.x = cvtpk(f.x, f.y);
      pk.y = cvtpk(f.z, f.w);
      *(uint2*)((char*)smem + n * 128 + (((ch >> 1) ^ (n & 7)) << 4) + ((ch & 1) << 3)) = pk;
    }
  }
  __syncthreads();  // image + params visible

  // ---- key B-fragments from LDS (cols 0..3 read keys, 4..7 write keys)
  bf16x8 kb0 = {}, kb1 = {};
  if (p < 8) {
    kb0 = *(const bf16x8*)&knbs[p * 64 + q * 8];
    kb1 = *(const bf16x8*)&knbs[p * 64 + 32 + q * 8];
  }

  // ---- MFMA score pass over wave-owned rows: scores for head hj + Gram norms
  auto score_pass = [&](int hj) {
#pragma unroll
    for (int tt = 0; tt < 4; ++tt) {
      const int tile = w * 4 + tt;
      const int row = tile * 16 + p;
      const bf16x8 a0 = *(const bf16x8*)((char*)smem + row * 128 + (((q) ^ (row & 7)) << 4));
      const bf16x8 a1 = *(const bf16x8*)((char*)smem + row * 128 + (((q + 4) ^ (row & 7)) << 4));
      f32x4 sacc = {0.f, 0.f, 0.f, 0.f}, gacc = {0.f, 0.f, 0.f, 0.f};
      sacc = __builtin_amdgcn_mfma_f32_16x16x32_bf16(a0, kb0, sacc, 0, 0, 0);
      sacc = __builtin_amdgcn_mfma_f32_16x16x32_bf16(a1, kb1, sacc, 0, 0, 0);
      gacc = __builtin_amdgcn_mfma_f32_16x16x32_bf16(a0, a0, gacc, 0, 0, 0);
      gacc = __builtin_amdgcn_mfma_f32_16x16x32_bf16(a1, a1, gacc, 0, 0, 0);
      if (p == hj)       *(f32x4*)&Ar[tile * 16 + q * 4] = sacc;
      if (p == 4 + hj)   *(f32x4*)&Aw[tile * 16 + q * 4] = sacc;
      if ((p >> 2) == q) nrm_s[tile * 16 + p] = gacc[p & 3];
    }
  };

  score_pass(0);
  __syncthreads();  // head-0 scores + norms visible

  const int h = t >> 9;      // 0: read half (waves 0-7), 1: write half (8-15)
  const int th = t & 511;
  float* Abuf = h ? Aw : Ar;
  float* Wbuf = h ? wpW : wpR;

  for (int i = 0; i < 4; ++i) {
    const float beta = parb[h * 4 + i][0], g = parb[h * 4 + i][1];
    const float sh0 = parb[h * 4 + i][2], sh1 = parb[h * 4 + i][3], sh2 = parb[h * 4 + i][4];
    const float gamma = parb[h * 4 + i][5];
    const float* prevw = (h ? prev_w_w : prev_w_r) + ((size_t)i * 512 + b) * 1024;

    // ---- P1: stage prevw (bf16) + unscaled exp of cosine-normalized scores
    const float pv0 = prevw[th];
    const float pv1 = prevw[th + 512];
    float e2[2];
    float s = 0.f;
#pragma unroll
    for (int k = 0; k < 2; ++k) {
      const int u = th + 512 * k;
      const float z = beta * Abuf[u] / (sqrtf(nrm_s[u]) + EPS_);
      e2[k] = __expf(z);
      s += e2[k];
    }
    Abuf[th] = e2[0];
    Abuf[th + 512] = e2[1];
    pwbs[h][th] = (unsigned short)f2bf(pv0);
    pwbs[h][th + 512] = (unsigned short)f2bf(pv1);
#pragma unroll
    for (int off = 32; off > 0; off >>= 1) s += __shfl_xor(s, off);
    if (l == 0) redB[w] = s;
    __syncthreads();  // S1

    // ---- P2: gate + shift + sharpen (softmax scale folded into gi)
    float gsum = 0.f;
#pragma unroll
    for (int j = 0; j < 8; ++j) gsum += redB[h * 8 + j];
    const float gi = g / gsum;
    const float gm = 1.f - g;
    float s2 = 0.f;
#pragma unroll
    for (int k = 0; k < 2; ++k) {
      const int u = th + 512 * k;
      const int um = (u + 1023) & 1023, up = (u + 1) & 1023;
      const float wgm = gi * Abuf[um] + gm * bflo2f((unsigned)pwbs[h][um]);
      const float wg0 = gi * Abuf[u] + gm * bflo2f((unsigned)pwbs[h][u]);
      const float wgp = gi * Abuf[up] + gm * bflo2f((unsigned)pwbs[h][up]);
      const float ws = sh0 * wgm + sh1 * wg0 + sh2 * wgp;
      const float wp = (ws > 0.f) ? exp2f(gamma * __log2f(ws)) : 0.f;
      Wbuf[u] = wp;
      s2 += wp;
    }
#pragma unroll
    for (int off = 32; off > 0; off >>= 1) s2 += __shfl_xor(s2, off);
    if (l == 0) redC[w] = s2;
    __syncthreads();  // S2

    // ---- P3: sweep wave-owned rows (reads + in-place update, read-side norm)
    float ir = 0.f, iw = 0.f;
#pragma unroll
    for (int j = 0; j < 8; ++j) { ir += redC[j]; iw += redC[8 + j]; }
    const float inv2r = 1.f / (ir + EPS_);
    const float inv2w = 1.f / (iw + EPS_);

    float e_0 = 0.f, e_1 = 0.f, e_2 = 0.f, e_3 = 0.f;
    float a_0 = 0.f, a_1 = 0.f, a_2 = 0.f, a_3 = 0.f;
    if (i < 3) {
      const unsigned ue0 = ebp[i][p * 2], ue1 = ebp[i][p * 2 + 1];
      const unsigned ua0 = abp[i][p * 2], ua1 = abp[i][p * 2 + 1];
      e_0 = bflo2f(ue0); e_1 = bfhi2f(ue0); e_2 = bflo2f(ue1); e_3 = bfhi2f(ue1);
      a_0 = bflo2f(ua0); a_1 = bfhi2f(ua0); a_2 = bflo2f(ua1); a_3 = bfhi2f(ua1);
    }

    float r[4] = {0.f, 0.f, 0.f, 0.f};
#pragma unroll 4
    for (int it = 0; it < 16; ++it) {
      const int row = w * 64 + it * 4 + q;
      char* addr = (char*)smem + row * 128 + (((p >> 1) ^ (row & 7)) << 4) + ((p & 1) << 3);
      uint2 pk = *(uint2*)addr;
      const float v0 = bflo2f(pk.x), v1 = bfhi2f(pk.x);
      const float v2 = bflo2f(pk.y), v3 = bfhi2f(pk.y);
      const float wr = wpR[row] * inv2r;
      r[0] = fmaf(wr, v0, r[0]); r[1] = fmaf(wr, v1, r[1]);
      r[2] = fmaf(wr, v2, r[2]); r[3] = fmaf(wr, v3, r[3]);
      if (i < 3) {
        const float ww = wpW[row] * inv2w;
        const float n0 = fmaf(v0, fmaf(-ww, e_0, 1.f), ww * a_0);
        const float n1 = fmaf(v1, fmaf(-ww, e_1, 1.f), ww * a_1);
        const float n2 = fmaf(v2, fmaf(-ww, e_2, 1.f), ww * a_2);
        const float n3 = fmaf(v3, fmaf(-ww, e_3, 1.f), ww * a_3);
        pk.x = cvtpk(n0, n1);
        pk.y = cvtpk(n2, n3);
        *(uint2*)addr = pk;
      }
    }
    // fold read partials over the 4 q-groups (lane bits 4,5)
#pragma unroll
    for (int c = 0; c < 4; ++c) {
      r[c] += __shfl_xor(r[c], 16);
      r[c] += __shfl_xor(r[c], 32);
    }
    if (q == 0) *(f32x4*)&racc[w][p * 4] = *(f32x4*)r;

    if (i < 3) score_pass(i + 1);  // own-row scores/norms from updated image
    __syncthreads();               // S3

    if (t < 64) {
      float s3 = 0.f;
#pragma unroll
      for (int wv = 0; wv < 16; ++wv) s3 += racc[wv][t];
      Aoutb[(size_t)b * 768 + 512 + i * 64 + t] = (unsigned short)f2bf(s3);
    }
  }
}

extern "C" void kernel_launch(void* const* d_in, const int* in_sizes, int n_in,
                              void* d_out, int out_size, void* d_ws, size_t ws_size,
                              hipStream_t stream) {
  (void)in_sizes; (void)n_in; (void)out_size; (void)ws_size;
  const float* in_data = (const float*)d_in[0];
  const float* memory = (const float*)d_in[1];
  const float* prev_reads = (const float*)d_in[2];
  const float* prev_w_r = (const float*)d_in[3];
  const float* prev_w_w = (const float*)d_in[4];
  const float* h0 = (const float*)d_in[5];
  const float* c0 = (const float*)d_in[6];
  const float* W_ih = (const float*)d_in[7];
  const float* b_ih = (const float*)d_in[8];
  const float* W_hh = (const float*)d_in[9];
  const float* b_hh = (const float*)d_in[10];
  const float* W_rh = (const float*)d_in[11];
  const float* b_rh = (const float*)d_in[12];
  const float* W_wh = (const float*)d_in[13];
  const float* b_wh = (const float*)d_in[14];
  const float* W_out = (const float*)d_in[15];
  const float* b_out = (const float*)d_in[16];
  float* out = (float*)d_out;

  char* base = (char*)d_ws;
  auto alloc = [&](size_t bytes) -> char* {
    char* p = base; base += (bytes + 255) & ~(size_t)255; return p;
  };
  unsigned short* x2b   = (unsigned short*)alloc((size_t)512 * 1024 * 2);
  unsigned short* Wcatb = (unsigned short*)alloc((size_t)2048 * 1024 * 2);
  float* bcat           = (float*)alloc(2048 * 4);
  float* gates          = (float*)alloc((size_t)512 * 2048 * 4);
  unsigned short* W2b   = (unsigned short*)alloc((size_t)1072 * 512 * 2);
  float* bcat2          = (float*)alloc(1072 * 4);
  unsigned short* Woutb = (unsigned short*)alloc((size_t)256 * 768 * 2);
  float* P              = (float*)alloc((size_t)512 * 1072 * 4);
  unsigned short* Aoutb = (unsigned short*)alloc((size_t)512 * 768 * 2);

  k_prep<<<2048, 256, 0, stream>>>(in_data, prev_reads, h0, W_ih, W_hh, b_ih, b_hh,
                                   W_rh, W_wh, W_out, b_rh, b_wh,
                                   x2b, Wcatb, bcat, W2b, Woutb, bcat2);
  k_gemm_mfma<false><<<dim3(64, 16), 64, 0, stream>>>(x2b, 1024, Wcatb, bcat, gates, 2048, 1024, 2048);
  k_lstm<<<1024, 256, 0, stream>>>(gates, c0, Aoutb);
  k_gemm_mfma<false><<<dim3(34, 16), 64, 0, stream>>>(Aoutb, 768, W2b, bcat2, P, 1072, 512, 1072);
  k_mega<<<512, 1024, 0, stream>>>(memory, P, prev_w_r, prev_w_w, Aoutb);
  k_gemm_mfma<true><<<dim3(8, 16), 64, 0, stream>>>(Aoutb, 768, Woutb, b_out, out, 256, 768, 256);
}

// Round 12
// 120.642 us; speedup vs baseline: 1.8189x; 1.0198x over previous
//
#include <hip/hip_runtime.h>
#include <cmath>

#define B_ 512
#define EPS_ 1e-8f

typedef __bf16 bf16x8 __attribute__((ext_vector_type(8)));
typedef float f32x4 __attribute__((ext_vector_type(4)));

__device__ __forceinline__ float sigmoidf_(float x) { return 1.f / (1.f + expf(-x)); }
__device__ __forceinline__ float softplusf_(float x) { return x > 20.f ? x : log1pf(expf(x)); }
__device__ __forceinline__ unsigned f2bf(float x) {
  union { float f; unsigned u; } v; v.f = x;
  unsigned r = v.u + 0x7FFF + ((v.u >> 16) & 1);
  return r >> 16;
}
__device__ __forceinline__ float bfhi2f(unsigned u) { return __uint_as_float(u & 0xffff0000u); }
__device__ __forceinline__ float bflo2f(unsigned u) { return __uint_as_float(u << 16); }
// packed f32->bf16 (RNE), lo = a, hi = b
__device__ __forceinline__ unsigned cvtpk(float a, float b) {
  unsigned r;
  asm("v_cvt_pk_bf16_f32 %0, %1, %2" : "=v"(r) : "v"(a), "v"(b));
  return r;
}
// raw v_rsq_f32 (~1e-6 rel) — replaces sqrtf+fdiv on score paths
__device__ __forceinline__ float rsq_(float x) {
  float r;
  asm("v_rsq_f32 %0, %1" : "=v"(r) : "v"(x));
  return r;
}

// ---------------- one prep kernel: x2b + all weight conversions (grid-stride)
__global__ void k_prep(const float* __restrict__ in_data, const float* __restrict__ prev_reads,
                       const float* __restrict__ h0,
                       const float* __restrict__ W_ih, const float* __restrict__ W_hh,
                       const float* __restrict__ b_ih, const float* __restrict__ b_hh,
                       const float* __restrict__ W_rh, const float* __restrict__ W_wh,
                       const float* __restrict__ W_out,
                       const float* __restrict__ b_rh, const float* __restrict__ b_wh,
                       unsigned short* __restrict__ x2b,
                       unsigned short* __restrict__ Wcatb, float* __restrict__ bcat,
                       unsigned short* __restrict__ W2b, unsigned short* __restrict__ Woutb,
                       float* __restrict__ bcat2) {
  const int stride = gridDim.x * blockDim.x;
  const int t0 = blockIdx.x * blockDim.x + threadIdx.x;
  for (int i = t0; i < 512 * 1024; i += stride) {
    const int b = i >> 10, j = i & 1023;
    float v;
    if (j < 256) v = in_data[(size_t)b * 256 + j];
    else if (j < 512) { const int jj = j - 256; v = prev_reads[(size_t)(jj >> 6) * B_ * 64 + (size_t)b * 64 + (jj & 63)]; }
    else v = h0[(size_t)b * 512 + (j - 512)];
    x2b[i] = (unsigned short)f2bf(v);
  }
  for (int i = t0; i < 2048 * 1024; i += stride) {
    const int j = i >> 10, k = i & 1023;
    Wcatb[i] = (unsigned short)f2bf(k < 512 ? W_ih[(size_t)j * 512 + k] : W_hh[(size_t)j * 512 + (k - 512)]);
  }
  for (int i = t0; i < 2048; i += stride) bcat[i] = b_ih[i] + b_hh[i];
  for (int i = t0; i < 143360; i += stride) W2b[i] = (unsigned short)f2bf(W_rh[i]);
  for (int i = t0; i < 405504; i += stride) W2b[143360 + i] = (unsigned short)f2bf(W_wh[i]);
  for (int i = t0; i < 196608; i += stride) Woutb[i] = (unsigned short)f2bf(W_out[i]);
  for (int i = t0; i < 280; i += stride) bcat2[i] = b_rh[i];
  for (int i = t0; i < 792; i += stride) bcat2[280 + i] = b_wh[i];
}

// ---------------- bf16 MFMA GEMM, one wave per 32x32 tile, direct-from-global frags
template <bool SIG>
__global__ __launch_bounds__(64) void k_gemm_mfma(const unsigned short* __restrict__ A, int lda,
                                                  const unsigned short* __restrict__ W,
                                                  const float* __restrict__ bias,
                                                  float* __restrict__ C,
                                                  int Nn, int Kk, int ldc) {
  const int l = threadIdx.x;
  const int m0 = blockIdx.y * 32, n0 = blockIdx.x * 32;
  const int lr = l & 15, lk = (l >> 4) * 8;
  f32x4 acc00 = {0.f, 0.f, 0.f, 0.f}, acc01 = acc00, acc10 = acc00, acc11 = acc00;
  const size_t pa0 = (size_t)(m0 + lr) * lda + lk;
  const size_t pa1 = pa0 + (size_t)16 * lda;
  const bool bok0 = (n0 + lr) < Nn, bok1 = (n0 + 16 + lr) < Nn;
  const size_t pb0 = (size_t)(n0 + lr) * Kk + lk;
  const size_t pb1 = pb0 + (size_t)16 * Kk;
#pragma unroll 4
  for (int k0 = 0; k0 < Kk; k0 += 32) {
    bf16x8 a0 = *(const bf16x8*)(A + pa0 + k0);
    bf16x8 a1 = *(const bf16x8*)(A + pa1 + k0);
    bf16x8 b0 = {}, b1 = {};
    if (bok0) b0 = *(const bf16x8*)(W + pb0 + k0);
    if (bok1) b1 = *(const bf16x8*)(W + pb1 + k0);
    acc00 = __builtin_amdgcn_mfma_f32_16x16x32_bf16(a0, b0, acc00, 0, 0, 0);
    acc01 = __builtin_amdgcn_mfma_f32_16x16x32_bf16(a0, b1, acc01, 0, 0, 0);
    acc10 = __builtin_amdgcn_mfma_f32_16x16x32_bf16(a1, b0, acc10, 0, 0, 0);
    acc11 = __builtin_amdgcn_mfma_f32_16x16x32_bf16(a1, b1, acc11, 0, 0, 0);
  }
  const int orow = (l >> 4) * 4;
  f32x4 accs[2][2] = {{acc00, acc01}, {acc10, acc11}};
#pragma unroll
  for (int mi = 0; mi < 2; ++mi) {
#pragma unroll
    for (int nj = 0; nj < 2; ++nj) {
      const int n = n0 + nj * 16 + lr;
      if (n < Nn) {
        const float bv = bias[n];
#pragma unroll
        for (int r = 0; r < 4; ++r) {
          const int m = m0 + mi * 16 + orow + r;
          float v = accs[mi][nj][r] + bv;
          if (SIG) v = 1.f / (1.f + expf(-v));
          C[(size_t)m * ldc + n] = v;
        }
      }
    }
  }
}

// ---------------- LSTM pointwise -> h (bf16) into Aoutb rows (stride 768)
__global__ void k_lstm(const float* __restrict__ gates, const float* __restrict__ c0,
                       unsigned short* __restrict__ Aoutb) {
  const int idx = blockIdx.x * blockDim.x + threadIdx.x;  // < 512*512
  const int b = idx >> 9, j = idx & 511;
  const float* g = gates + (size_t)b * 2048;
  const float ig = g[j], fg = g[512 + j], gg = g[1024 + j], og = g[1536 + j];
  const float c = sigmoidf_(fg) * c0[idx] + sigmoidf_(ig) * tanhf(gg);
  Aoutb[(size_t)b * 768 + j] = (unsigned short)f2bf(sigmoidf_(og) * tanhf(c));
}

// ---------------- fused NTM head loop: one 1024-thread block per batch row.
// LDS bf16 memory image (XOR-swizzled 16B chunks), MFMA scores + Gram norms.
// 3 barriers/head. r12 instruction diet: P2 neighbors via shfl (boundary table
// pb instead of the pwbs LDS array), v_rsq_f32 for norms, sweep base-pointer
// hoisting (row&7 alternates {q, q+4}).
// NOTE (r7-r10): 1024-thread blocks are HARD-CAPPED at 64 VGPR regardless of
// launch_bounds 2nd arg; register-resident memory images spill (1 GB scratch).
// Keep the image in LDS (~56 VGPR used).
__global__ __launch_bounds__(1024, 4) void k_mega(const float* __restrict__ mem0,
                                                  const float* __restrict__ P,
                                                  const float* __restrict__ prev_w_r,
                                                  const float* __restrict__ prev_w_w,
                                                  unsigned short* __restrict__ Aoutb) {
  const int b = blockIdx.x;
  const int t = threadIdx.x;   // 1024
  const int l = t & 63;
  const int w = t >> 6;        // wave 0..15
  const int p = l & 15;
  const int q = l >> 4;        // 0..3

  __shared__ unsigned short smem[65536];                 // 1024x64 bf16 image (128 KB)
  __shared__ float Ar[1024], Aw[1024];                   // scores -> pe
  __shared__ float nrm_s[1024];                          // Gram-diag norms
  __shared__ float wpR[1024], wpW[1024];                 // unnormalized final weights
  __shared__ float racc[16][64];
  __shared__ unsigned short knbs[512];                   // 8 keys x 64 cols (bf16)
  __shared__ float parb[8][8];
  __shared__ unsigned ebp[4][32], abp[4][32];            // packed bf16 erase/add
  __shared__ float pb[2][16][2];                         // prevw chunk-boundary values
  __shared__ float redB[16], redC[16];

  // ---- params phase (waves 0..7: unit = type*4+head)
  if (w < 8) {
    const int type = w >> 2, head = w & 3;
    const float* pp = P + (size_t)b * 1072 + (type == 0 ? head * 70 : 280 + head * 198);
    const float kv = tanhf(pp[l]);
    float ss = kv * kv;
#pragma unroll
    for (int off = 32; off > 0; off >>= 1) ss += __shfl_xor(ss, off);
    knbs[w * 64 + l] = (unsigned short)f2bf(kv * rsq_(fmaxf(ss, 1e-20f)));
    if (l == 0) {
      parb[w][0] = softplusf_(pp[64]);
      parb[w][1] = sigmoidf_(pp[65]);
      const float s0 = pp[66], s1 = pp[67], s2 = pp[68];
      const float mx = fmaxf(s0, fmaxf(s1, s2));
      const float e0 = expf(s0 - mx), e1 = expf(s1 - mx), e2 = expf(s2 - mx);
      const float inv = 1.f / (e0 + e1 + e2);
      parb[w][2] = e0 * inv; parb[w][3] = e1 * inv; parb[w][4] = e2 * inv;
      parb[w][5] = 1.f + softplusf_(pp[69]);
    }
    if (type == 1 && l < 32) {
      ebp[head][l] = cvtpk(sigmoidf_(pp[70 + 2 * l]), sigmoidf_(pp[70 + 2 * l + 1]));
      abp[head][l] = cvtpk(tanhf(pp[134 + 2 * l]), tanhf(pp[134 + 2 * l + 1]));
    }
  }

  // ---- staging: f32 memory -> bf16 LDS image (swizzled 16B chunks)
  {
    const float4* src = (const float4*)(mem0 + (size_t)b * 65536);
#pragma unroll 4
    for (int k = 0; k < 16; ++k) {
      const int v = k * 1024 + t;          // float4 index; n = v>>4, ch = v&15
      const float4 f = src[v];
      const int n = v >> 4, ch = v & 15;
      uint2 pk;
      pk.x = cvtpk(f.x, f.y);
      pk.y = cvtpk(f.z, f.w);
      *(uint2*)((char*)smem + n * 128 + (((ch >> 1) ^ (n & 7)) << 4) + ((ch & 1) << 3)) = pk;
    }
  }
  __syncthreads();  // image + params visible

  // ---- key B-fragments from LDS (cols 0..3 read keys, 4..7 write keys)
  bf16x8 kb0 = {}, kb1 = {};
  if (p < 8) {
    kb0 = *(const bf16x8*)&knbs[p * 64 + q * 8];
    kb1 = *(const bf16x8*)&knbs[p * 64 + 32 + q * 8];
  }

  // ---- MFMA score pass over wave-owned rows: scores for head hj + Gram norms
  auto score_pass = [&](int hj) {
#pragma unroll
    for (int tt = 0; tt < 4; ++tt) {
      const int tile = w * 4 + tt;
      const int row = tile * 16 + p;
      const bf16x8 a0 = *(const bf16x8*)((char*)smem + row * 128 + (((q) ^ (row & 7)) << 4));
      const bf16x8 a1 = *(const bf16x8*)((char*)smem + row * 128 + (((q + 4) ^ (row & 7)) << 4));
      f32x4 sacc = {0.f, 0.f, 0.f, 0.f}, gacc = {0.f, 0.f, 0.f, 0.f};
      sacc = __builtin_amdgcn_mfma_f32_16x16x32_bf16(a0, kb0, sacc, 0, 0, 0);
      sacc = __builtin_amdgcn_mfma_f32_16x16x32_bf16(a1, kb1, sacc, 0, 0, 0);
      gacc = __builtin_amdgcn_mfma_f32_16x16x32_bf16(a0, a0, gacc, 0, 0, 0);
      gacc = __builtin_amdgcn_mfma_f32_16x16x32_bf16(a1, a1, gacc, 0, 0, 0);
      if (p == hj)       *(f32x4*)&Ar[tile * 16 + q * 4] = sacc;
      if (p == 4 + hj)   *(f32x4*)&Aw[tile * 16 + q * 4] = sacc;
      if ((p >> 2) == q) nrm_s[tile * 16 + p] = gacc[p & 3];
    }
  };

  score_pass(0);
  __syncthreads();  // head-0 scores + norms visible

  const int h = t >> 9;      // 0: read half (waves 0-7), 1: write half (8-15)
  const int th = t & 511;
  const int w8 = (t & 511) >> 6;   // chunk index within half (0..7)
  float* Abuf = h ? Aw : Ar;
  float* Wbuf = h ? wpW : wpR;

  for (int i = 0; i < 4; ++i) {
    const float beta = parb[h * 4 + i][0], g = parb[h * 4 + i][1];
    const float sh0 = parb[h * 4 + i][2], sh1 = parb[h * 4 + i][3], sh2 = parb[h * 4 + i][4];
    const float gamma = parb[h * 4 + i][5];
    const float* prevw = (h ? prev_w_w : prev_w_r) + ((size_t)i * 512 + b) * 1024;

    // ---- P1: prevw -> regs (+ boundary table) + unscaled exp of scores
    const float pv0 = prevw[th];
    const float pv1 = prevw[th + 512];
    float e2_[2];
    float s = 0.f;
#pragma unroll
    for (int k = 0; k < 2; ++k) {
      const int u = th + 512 * k;
      const float z = beta * Abuf[u] * rsq_(fmaxf(nrm_s[u], 1e-20f));
      e2_[k] = __expf(z);
      s += e2_[k];
    }
    Abuf[th] = e2_[0];
    Abuf[th + 512] = e2_[1];
    if (l == 0)  { pb[h][w8][0] = pv0; pb[h][w8 + 8][0] = pv1; }
    if (l == 63) { pb[h][w8][1] = pv0; pb[h][w8 + 8][1] = pv1; }
#pragma unroll
    for (int off = 32; off > 0; off >>= 1) s += __shfl_xor(s, off);
    if (l == 0) redB[w] = s;
    __syncthreads();  // S1

    // ---- P2: gate + shift + sharpen; neighbors via shfl, boundaries via pb
    float gsum = 0.f;
#pragma unroll
    for (int j = 0; j < 8; ++j) gsum += redB[h * 8 + j];
    const float gi = g / gsum;
    const float gm = 1.f - g;
    float s2 = 0.f;
#pragma unroll
    for (int k = 0; k < 2; ++k) {
      const int u = th + 512 * k;
      const float wg0 = gi * Abuf[u] + gm * ((k == 0) ? pv0 : pv1);
      float wgm = __shfl_up(wg0, 1);
      float wgp = __shfl_down(wg0, 1);
      if (l == 0) {
        const int um = (u + 1023) & 1023;
        wgm = gi * Abuf[um] + gm * pb[h][um >> 6][1];
      }
      if (l == 63) {
        const int up = (u + 1) & 1023;
        wgp = gi * Abuf[up] + gm * pb[h][up >> 6][0];
      }
      const float ws = sh0 * wgm + sh1 * wg0 + sh2 * wgp;
      const float wp = (ws > 0.f) ? exp2f(gamma * __log2f(ws)) : 0.f;
      Wbuf[u] = wp;
      s2 += wp;
    }
#pragma unroll
    for (int off = 32; off > 0; off >>= 1) s2 += __shfl_xor(s2, off);
    if (l == 0) redC[w] = s2;
    __syncthreads();  // S2

    // ---- P3: sweep wave-owned rows (reads + in-place update, read-side norm)
    float ir = 0.f, iw = 0.f;
#pragma unroll
    for (int j = 0; j < 8; ++j) { ir += redC[j]; iw += redC[8 + j]; }
    const float inv2r = 1.f / (ir + EPS_);
    const float inv2w = 1.f / (iw + EPS_);

    float e_0 = 0.f, e_1 = 0.f, e_2 = 0.f, e_3 = 0.f;
    float a_0 = 0.f, a_1 = 0.f, a_2 = 0.f, a_3 = 0.f;
    if (i < 3) {
      const unsigned ue0 = ebp[i][p * 2], ue1 = ebp[i][p * 2 + 1];
      const unsigned ua0 = abp[i][p * 2], ua1 = abp[i][p * 2 + 1];
      e_0 = bflo2f(ue0); e_1 = bfhi2f(ue0); e_2 = bflo2f(ue1); e_3 = bfhi2f(ue1);
      a_0 = bflo2f(ua0); a_1 = bfhi2f(ua0); a_2 = bflo2f(ua1); a_3 = bfhi2f(ua1);
    }

    // two hoisted swizzled base pointers: rows w*64+{q, 4+q} (+8 per step)
    char* const base0 = (char*)smem + (w * 64 + q) * 128 + ((((p >> 1) ^ q) << 4) | ((p & 1) << 3));
    char* const base1 = (char*)smem + (w * 64 + 4 + q) * 128 + ((((p >> 1) ^ (4 + q)) << 4) | ((p & 1) << 3));
    float r[4] = {0.f, 0.f, 0.f, 0.f};
#pragma unroll 2
    for (int it2 = 0; it2 < 8; ++it2) {
      {
        const int row = w * 64 + it2 * 8 + q;
        char* addr = base0 + it2 * 1024;
        uint2 pk = *(uint2*)addr;
        const float v0 = bflo2f(pk.x), v1 = bfhi2f(pk.x);
        const float v2 = bflo2f(pk.y), v3 = bfhi2f(pk.y);
        const float wr = wpR[row] * inv2r;
        r[0] = fmaf(wr, v0, r[0]); r[1] = fmaf(wr, v1, r[1]);
        r[2] = fmaf(wr, v2, r[2]); r[3] = fmaf(wr, v3, r[3]);
        if (i < 3) {
          const float ww = wpW[row] * inv2w;
          pk.x = cvtpk(fmaf(v0, fmaf(-ww, e_0, 1.f), ww * a_0),
                       fmaf(v1, fmaf(-ww, e_1, 1.f), ww * a_1));
          pk.y = cvtpk(fmaf(v2, fmaf(-ww, e_2, 1.f), ww * a_2),
                       fmaf(v3, fmaf(-ww, e_3, 1.f), ww * a_3));
          *(uint2*)addr = pk;
        }
      }
      {
        const int row = w * 64 + it2 * 8 + 4 + q;
        char* addr = base1 + it2 * 1024;
        uint2 pk = *(uint2*)addr;
        const float v0 = bflo2f(pk.x), v1 = bfhi2f(pk.x);
        const float v2 = bflo2f(pk.y), v3 = bfhi2f(pk.y);
        const float wr = wpR[row] * inv2r;
        r[0] = fmaf(wr, v0, r[0]); r[1] = fmaf(wr, v1, r[1]);
        r[2] = fmaf(wr, v2, r[2]); r[3] = fmaf(wr, v3, r[3]);
        if (i < 3) {
          const float ww = wpW[row] * inv2w;
          pk.x = cvtpk(fmaf(v0, fmaf(-ww, e_0, 1.f), ww * a_0),
                       fmaf(v1, fmaf(-ww, e_1, 1.f), ww * a_1));
          pk.y = cvtpk(fmaf(v2, fmaf(-ww, e_2, 1.f), ww * a_2),
                       fmaf(v3, fmaf(-ww, e_3, 1.f), ww * a_3));
          *(uint2*)addr = pk;
        }
      }
    }
    // fold read partials over the 4 q-groups (lane bits 4,5)
#pragma unroll
    for (int c = 0; c < 4; ++c) {
      r[c] += __shfl_xor(r[c], 16);
      r[c] += __shfl_xor(r[c], 32);
    }
    if (q == 0) *(f32x4*)&racc[w][p * 4] = *(f32x4*)r;

    if (i < 3) score_pass(i + 1);  // own-row scores/norms from updated image
    __syncthreads();               // S3

    if (t < 64) {
      float s3 = 0.f;
#pragma unroll
      for (int wv = 0; wv < 16; ++wv) s3 += racc[wv][t];
      Aoutb[(size_t)b * 768 + 512 + i * 64 + t] = (unsigned short)f2bf(s3);
    }
  }
}

extern "C" void kernel_launch(void* const* d_in, const int* in_sizes, int n_in,
                              void* d_out, int out_size, void* d_ws, size_t ws_size,
                              hipStream_t stream) {
  (void)in_sizes; (void)n_in; (void)out_size; (void)ws_size;
  const float* in_data = (const float*)d_in[0];
  const float* memory = (const float*)d_in[1];
  const float* prev_reads = (const float*)d_in[2];
  const float* prev_w_r = (const float*)d_in[3];
  const float* prev_w_w = (const float*)d_in[4];
  const float* h0 = (const float*)d_in[5];
  const float* c0 = (const float*)d_in[6];
  const float* W_ih = (const float*)d_in[7];
  const float* b_ih = (const float*)d_in[8];
  const float* W_hh = (const float*)d_in[9];
  const float* b_hh = (const float*)d_in[10];
  const float* W_rh = (const float*)d_in[11];
  const float* b_rh = (const float*)d_in[12];
  const float* W_wh = (const float*)d_in[13];
  const float* b_wh = (const float*)d_in[14];
  const float* W_out = (const float*)d_in[15];
  const float* b_out = (const float*)d_in[16];
  float* out = (float*)d_out;

  char* base = (char*)d_ws;
  auto alloc = [&](size_t bytes) -> char* {
    char* p = base; base += (bytes + 255) & ~(size_t)255; return p;
  };
  unsigned short* x2b   = (unsigned short*)alloc((size_t)512 * 1024 * 2);
  unsigned short* Wcatb = (unsigned short*)alloc((size_t)2048 * 1024 * 2);
  float* bcat           = (float*)alloc(2048 * 4);
  float* gates          = (float*)alloc((size_t)512 * 2048 * 4);
  unsigned short* W2b   = (unsigned short*)alloc((size_t)1072 * 512 * 2);
  float* bcat2          = (float*)alloc(1072 * 4);
  unsigned short* Woutb = (unsigned short*)alloc((size_t)256 * 768 * 2);
  float* P              = (float*)alloc((size_t)512 * 1072 * 4);
  unsigned short* Aoutb = (unsigned short*)alloc((size_t)512 * 768 * 2);

  k_prep<<<2048, 256, 0, stream>>>(in_data, prev_reads, h0, W_ih, W_hh, b_ih, b_hh,
                                   W_rh, W_wh, W_out, b_rh, b_wh,
                                   x2b, Wcatb, bcat, W2b, Woutb, bcat2);
  k_gemm_mfma<false><<<dim3(64, 16), 64, 0, stream>>>(x2b, 1024, Wcatb, bcat, gates, 2048, 1024, 2048);
  k_lstm<<<1024, 256, 0, stream>>>(gates, c0, Aoutb);
  k_gemm_mfma<false><<<dim3(34, 16), 64, 0, stream>>>(Aoutb, 768, W2b, bcat2, P, 1072, 512, 1072);
  k_mega<<<512, 1024, 0, stream>>>(memory, P, prev_w_r, prev_w_w, Aoutb);
  k_gemm_mfma<true><<<dim3(8, 16), 64, 0, stream>>>(Aoutb, 768, Woutb, b_out, out, 256, 768, 256);
}